// Round 8
// baseline (386.439 us; speedup 1.0000x reference)
//
#include <hip/hip_runtime.h>

typedef unsigned short u16;
typedef __attribute__((ext_vector_type(8))) short bf16x8;   // 8 bf16 in 4 VGPRs
typedef __attribute__((ext_vector_type(4))) float f32x4;

__device__ __forceinline__ u16 f2bf(float f) {
    unsigned u = __float_as_uint(f);
    u += 0x7fffu + ((u >> 16) & 1u);   // round-to-nearest-even
    return (u16)(u >> 16);
}

__device__ __forceinline__ void g2l16(const void* g, void* l) {
    __builtin_amdgcn_global_load_lds((const __attribute__((address_space(1))) void*)g,
                                     (__attribute__((address_space(3))) void*)l, 16, 0, 0);
}

// Packed-triangular score layout (per batch, fp32 units):
//   block-row by (rows by*128..by*128+127) has row length L=(by+1)*128 and
//   base P(by) = 16384 * by*(by+1)/2.  Total = 16384*136 = 2,228,224 fp32
//   (8.9 MB/batch vs 16.8 dense) -> zc=8 fits in 204 MB of workspace.
#define SPACK_ELEMS 2228224LL

// ---------------------------------------------------------------------------
// GEMM: C[M,N] = alpha * A[M,K] @ B^T  where B is stored [N,K] row-major.
// bf16 in, fp32 accum. 128x128 tile, BK=64, 4 waves x (4x4 of 16x16x32 MFMA).
// 4 blocks/CU (32 KiB LDS) — inter-block overlap covers barrier drains
// (m114 mechanism); measured 46% MfmaUtil / ~1000 TF on the qkv shape.
// DO NOT: (a) 256^2 8-phase port (round 2: 1 block/CU, whole-CU barrier
// stalls, 34% MfmaUtil; correct re-port needs full derived-waits schedule);
// (b) merge independent GEMMs into one launch (round 3: FETCH 144->509 MB,
// L2 panel locality destroyed); (c) split qkv M into two launches (round 5:
// 1.5 residency rounds -> idle tail, 105->114 us); (d) AV CU-targeted
// by-permutations (rounds 6-7: PERM and magic-square both neutral-to-negative
// vs plain h>>3 — all 128 blocks/XCD co-resident at t=0, panel adjacency
// dominates; keep same-by blocks adjacent).
//
// BATCH<->XCD ALIGNMENT (round 5, measured win): modes 1 and 2 run 8 batches
// on 8 XCDs. Natural grids slice XCD = linear%8 ACROSS batches -> every XCD
// touches every batch (S-GEMM FETCH 215 MB vs 64 ideal). When gridDim.z == 8
// we remap  g = linear_id; batch = g & 7; work = g >> 3  so each XCD runs one
// batch (per-XCD working set 8-8.5 MB vs 4 MiB L2, temporal panel clustering).
// Measured: attention GEMMs 82 -> ~57 us, FETCH 215 -> 73 MB.
//
// mode 0: plain grid.
// mode 1: packed lower-triangle grid; C written into packed-triangular S.
// mode 2: K capped at (by+1)*128; A read from packed-tri S (bf16).
// ---------------------------------------------------------------------------
#define BM 128
#define BN 128
#define BK 64

template <bool OUT_BF16>
__global__ __launch_bounds__(256, 4) void gemm_bt(
    const u16* __restrict__ A, const u16* __restrict__ B, void* __restrict__ Cout,
    int K, int lda, int ldb, int ldc,
    long long sA, long long sB, long long sC,
    float alpha, int mode)
{
    int bx, by;
    int bz = blockIdx.z;
    if (mode == 1) {                       // packed triangle: l -> (bx<=by, by)
        int l;
        if (gridDim.z == 8) {              // batch<->XCD remap (see header)
            int g = (int)blockIdx.x + (int)gridDim.x * (int)blockIdx.z;
            bz = g & 7; l = g >> 3;        // l in [0, gridDim.x)
        } else {
            l = blockIdx.x;
        }
        by = (int)((sqrtf(8.f * (float)l + 1.f) - 1.f) * 0.5f);
        while ((by + 1) * (by + 2) / 2 <= l) ++by;
        while (by * (by + 1) / 2 > l) --by;
        bx = l - by * (by + 1) / 2;
    } else if (mode == 2) {                // causal K cap
        if (gridDim.z == 8) {              // batch<->XCD remap (round-5 form:
            int g = (int)blockIdx.x        //  bx fast, by slow -> same-by
                  + (int)gridDim.x * ((int)blockIdx.y   // blocks adjacent =
                  + (int)gridDim.y * (int)blockIdx.z);  // S-panel locality)
            bz = g & 7;
            int h = g >> 3;                // [0, 128)
            bx = h & 7;
            by = h >> 3;
        } else {                           // fallback: per-z row rotation
            bx = blockIdx.x;
            int byrev = ((int)blockIdx.y + 4 * ((int)blockIdx.z >> 1)) & 15;
            by = (int)gridDim.y - 1 - byrev;
        }
    } else {
        bx = blockIdx.x; by = blockIdx.y;
    }
    int Keff = K;
    if (mode == 2) { int cap = (by + 1) * BM; if (cap < Keff) Keff = cap; }

    __shared__ alignas(16) u16 As[BM * BK];
    __shared__ alignas(16) u16 Bs[BN * BK];

    const int tid  = threadIdx.x;
    const int wave = tid >> 6, lane = tid & 63;
    const int wm = wave >> 1, wn = wave & 1;
    const int q = lane >> 4, r = lane & 15;

    const long long Pby = 16384LL * (by * (by + 1) / 2);   // packed-tri base

    const u16* Ab;
    int lda_e = lda;
    if (mode == 2) {                       // A rows live in packed S (bf16 view)
        lda_e = 2 * (by + 1) * BM;         // u16 stride = fp32 row size
        Ab = A + sA * bz + 2 * Pby;
    } else {
        Ab = A + sA * bz + (size_t)(by * BM) * lda_e;
    }
    const u16* Bb = B + sB * bz + (size_t)(bx * BN) * ldb;

    // kt-invariant staging pointers (advance by BK elements per tile)
    const u16* ap[4]; const u16* bp[4]; int sb[4];
#pragma unroll
    for (int j = 0; j < 4; ++j) {
        int s   = (wave * 4 + j) * 64 + lane;
        int row = s >> 3;
        int cc  = (s & 7) ^ (row & 7);     // slot s holds global chunk cc of row
        ap[j] = Ab + (size_t)row * lda_e + cc * 8;
        bp[j] = Bb + (size_t)row * ldb + cc * 8;
        sb[j] = (wave * 4 + j) * 64;
    }

    f32x4 acc[4][4] = {};

    const int kiters = Keff / BK;
    for (int kt = 0; kt < kiters; ++kt) {
#pragma unroll
        for (int j = 0; j < 4; ++j) { g2l16(ap[j], As + (size_t)sb[j] * 8); ap[j] += BK; }
#pragma unroll
        for (int j = 0; j < 4; ++j) { g2l16(bp[j], Bs + (size_t)sb[j] * 8); bp[j] += BK; }
        __syncthreads();
#pragma unroll
        for (int ks = 0; ks < 2; ++ks) {   // two 32-wide k-steps per tile
            bf16x8 af[4], bfv[4];
#pragma unroll
            for (int i = 0; i < 4; ++i) {
                int mr = wm * 64 + i * 16 + r;
                int cc = (ks * 4 + q) ^ (mr & 7);
                af[i] = *(const bf16x8*)(As + mr * BK + cc * 8);
            }
#pragma unroll
            for (int i = 0; i < 4; ++i) {
                int nr = wn * 64 + i * 16 + r;
                int cc = (ks * 4 + q) ^ (nr & 7);
                bfv[i] = *(const bf16x8*)(Bs + nr * BK + cc * 8);
            }
#pragma unroll
            for (int i = 0; i < 4; ++i)
#pragma unroll
                for (int jn = 0; jn < 4; ++jn)
                    acc[i][jn] = __builtin_amdgcn_mfma_f32_16x16x32_bf16(
                        af[i], bfv[jn], acc[i][jn], 0, 0, 0);
        }
        __syncthreads();
    }

    // epilogue: C/D layout col=lane&15, row=(lane>>4)*4+reg
    if (mode == 1) {                       // packed-triangular fp32 write
        float* Cp = (float*)Cout + sC * bz + Pby;
        const int ldrow = (by + 1) * BM;
#pragma unroll
        for (int i = 0; i < 4; ++i) {
            int lr = wm * 64 + i * 16 + q * 4;            // local row in block-row
#pragma unroll
            for (int jn = 0; jn < 4; ++jn) {
                int col = bx * BN + wn * 64 + jn * 16 + r; // col < ldrow (bx<=by)
#pragma unroll
                for (int rr = 0; rr < 4; ++rr)
                    Cp[(size_t)(lr + rr) * ldrow + col] = acc[i][jn][rr] * alpha;
            }
        }
    } else if constexpr (OUT_BF16) {
        u16* Cp = (u16*)Cout + sC * bz;
#pragma unroll
        for (int i = 0; i < 4; ++i) {
            int rowb = by * BM + wm * 64 + i * 16 + q * 4;
#pragma unroll
            for (int jn = 0; jn < 4; ++jn) {
                int col = bx * BN + wn * 64 + jn * 16 + r;
#pragma unroll
                for (int rr = 0; rr < 4; ++rr)
                    Cp[(size_t)(rowb + rr) * ldc + col] = f2bf(acc[i][jn][rr] * alpha);
            }
        }
    } else {
        float* Cp = (float*)Cout + sC * bz;
#pragma unroll
        for (int i = 0; i < 4; ++i) {
            int rowb = by * BM + wm * 64 + i * 16 + q * 4;
#pragma unroll
            for (int jn = 0; jn < 4; ++jn) {
                int col = bx * BN + wn * 64 + jn * 16 + r;
#pragma unroll
                for (int rr = 0; rr < 4; ++rr)
                    Cp[(size_t)(rowb + rr) * ldc + col] = acc[i][jn][rr] * alpha;
            }
        }
    }
}

// ---------------------------------------------------------------------------
// Merged preprocessing (one launch instead of three): x cast + both weight
// transposes. Independent streaming jobs, whole-block divergence only,
// disjoint inputs/outputs -> no L2 coupling (unlike the round-3 GEMM merge).
//   block <  16384           : cast x fp32 -> bf16 (1024 elems/block)
//   block < 16384+3072       : transpose+cast Wqkv  [1024][3072] -> [3072][1024]
//   else (1024 blocks)       : transpose+cast Wproj [1024][1024] -> [1024][1024]
// ---------------------------------------------------------------------------
__global__ __launch_bounds__(256) void pre_cast_all(
    const float* __restrict__ x,     u16* __restrict__ xb,
    const float* __restrict__ Wqkv,  u16* __restrict__ WqkvT,
    const float* __restrict__ Wproj, u16* __restrict__ WprojT)
{
    __shared__ u16 tile[32][33];
    const int b = blockIdx.x;
    if (b < 16384) {
        int i = b * 256 + threadIdx.x;
        float4 f = ((const float4*)x)[i];
        ushort4 o;
        o.x = f2bf(f.x); o.y = f2bf(f.y); o.z = f2bf(f.z); o.w = f2bf(f.w);
        ((ushort4*)xb)[i] = o;
        return;
    }
    const float* in; u16* out; int R, Cc, c0, r0;
    if (b < 16384 + 3072) {
        int l = b - 16384;                 // original grid (96, 32), x fast
        in = Wqkv; out = WqkvT; R = 1024; Cc = 3072;
        c0 = (l % 96) * 32; r0 = (l / 96) * 32;
    } else {
        int l = b - 16384 - 3072;          // original grid (32, 32), x fast
        in = Wproj; out = WprojT; R = 1024; Cc = 1024;
        c0 = (l % 32) * 32; r0 = (l / 32) * 32;
    }
    const int tx = threadIdx.x & 31, ty = threadIdx.x >> 5;   // 32 x 8
#pragma unroll
    for (int k = 0; k < 4; ++k)
        tile[ty + k * 8][tx] = f2bf(in[(size_t)(r0 + ty + k * 8) * Cc + c0 + tx]);
    __syncthreads();
#pragma unroll
    for (int k = 0; k < 4; ++k)
        out[(size_t)(c0 + ty + k * 8) * R + r0 + tx] = tile[tx][ty + k * 8];
}

// In-place causal softmax on the PACKED-triangular S, one WAVE per row.
// Row t (block-row by=t>>7) has length L=(by+1)*128 fp32 at
// S + z*sS + P(by) + (t&127)*L. Reads fp32 scores [0,t], writes bf16
// probabilities over the same bytes, zero-filling [t+1, L).
// gridDim.y == 8: batch<->XCD remap so batch b's rows run on the XCD whose
// L2 holds b's S (written there by the S-GEMM) and feeds the AV GEMM.
__global__ __launch_bounds__(256) void softmax_causal_packed(
    float* __restrict__ S, long long sS)
{
    const int wave = threadIdx.x >> 6, lane = threadIdx.x & 63;
    int zb, xb;
    if (gridDim.y == 8) {
        int g = (int)blockIdx.x + (int)gridDim.x * (int)blockIdx.y;
        zb = g & 7; xb = g >> 3;           // [0, gridDim.x)
    } else {
        zb = blockIdx.y; xb = blockIdx.x;
    }
    const int t = xb * 4 + wave;
    const int by = t >> 7, lr = t & 127;
    const int L = (by + 1) << 7;
    float* row = S + (long long)zb * sS
               + 16384LL * (by * (by + 1) / 2) + (size_t)lr * L;
    const int n = t + 1;
    const int nit = (L + 255) >> 8;        // chunks of 64 lanes x 4 floats, <=8

    float v[32];
    float m = -1e30f;
    for (int it = 0; it < nit; ++it) {
        int c = it * 64 + lane;
        int e = c * 4;
        float4 f = make_float4(-1e30f, -1e30f, -1e30f, -1e30f);
        if (e < n) f = ((const float4*)row)[c];
        v[it * 4 + 0] = (e + 0 < n) ? f.x : -1e30f;
        v[it * 4 + 1] = (e + 1 < n) ? f.y : -1e30f;
        v[it * 4 + 2] = (e + 2 < n) ? f.z : -1e30f;
        v[it * 4 + 3] = (e + 3 < n) ? f.w : -1e30f;
        m = fmaxf(m, fmaxf(fmaxf(v[it * 4 + 0], v[it * 4 + 1]),
                           fmaxf(v[it * 4 + 2], v[it * 4 + 3])));
    }
    for (int off = 32; off > 0; off >>= 1) m = fmaxf(m, __shfl_xor(m, off));

    float s = 0.f;
    for (int it = 0; it < nit; ++it) {
#pragma unroll
        for (int j = 0; j < 4; ++j) {
            v[it * 4 + j] = __expf(v[it * 4 + j] - m);
            s += v[it * 4 + j];
        }
    }
    for (int off = 32; off > 0; off >>= 1) s += __shfl_xor(s, off);
    float inv = 1.f / s;

    u16* orow = (u16*)row;
    for (int it = 0; it < nit; ++it) {
        int c = it * 64 + lane;
        if (c * 4 < L) {
            ushort4 o;
            o.x = f2bf(v[it * 4 + 0] * inv);
            o.y = f2bf(v[it * 4 + 1] * inv);
            o.z = f2bf(v[it * 4 + 2] * inv);
            o.w = f2bf(v[it * 4 + 3] * inv);
            ((ushort4*)orow)[c] = o;
        }
    }
}

extern "C" void kernel_launch(void* const* d_in, const int* in_sizes, int n_in,
                              void* d_out, int out_size, void* d_ws, size_t ws_size,
                              hipStream_t stream)
{
    const float* x     = (const float*)d_in[0];
    const float* Wqkv  = (const float*)d_in[1];
    const float* Wproj = (const float*)d_in[2];
    float* out = (float*)d_out;

    const int Bb = 8, T = 2048, C1 = 1024, C3 = 3072;

    // Reassociation: out = (A@V)@Wp = A@(V@Wp); VWpT[b] = Wp^T@V^T computed
    // right after qkv, replacing the vT transpose AND the final proj GEMM.
    // VWpT overlays xb (dead after qkv); S is packed-triangular (8.9 MB/batch)
    // so the zc=8 high-water mark is 204 MB.
    char* ws = (char*)d_ws;
    u16*  xb     = (u16*)(ws);                       //  32 MB  x bf16 (dead post-qkv)
    u16*  VWpT   = (u16*)(ws);                       //  32 MB  overlay [B][C, T]
    u16*  WqkvT  = (u16*)(ws +  33554432ULL);        //   6 MB  [3C, C]
    u16*  WprojT = (u16*)(ws +  39845888ULL);        //   2 MB  [C, C]
    u16*  qkvb   = (u16*)(ws +  41943040ULL);        //  96 MB  [B*T, 3C]
    float* Sbuf  = (float*)(ws + 142606336ULL);      //  zc * 8.9 MB packed scores

    // largest batch-chunk whose packed score buffer fits the workspace
    const unsigned long long sbytes = SPACK_ELEMS * 4ULL;   // 8,912,896 B/batch
    int zc = 1;
    if      (ws_size >= 142606336ULL + 8ULL * sbytes) zc = 8;
    else if (ws_size >= 142606336ULL + 4ULL * sbytes) zc = 4;
    else if (ws_size >= 142606336ULL + 2ULL * sbytes) zc = 2;

    // 1. merged preprocessing: x cast + Wqkv transpose + Wproj transpose
    pre_cast_all<<<16384 + 3072 + 1024, 256, 0, stream>>>(
        x, xb, Wqkv, WqkvT, Wproj, WprojT);

    // 2. qkv = x @ Wqkv   [16384,1024]x[1024,3072] -> bf16 [16384,3072]
    //    Single launch: 3072 blocks = 12/CU = 3 full residency rounds
    gemm_bt<true><<<dim3(24, 128, 1), 256, 0, stream>>>(
        xb, WqkvT, qkvb, C1, C1, C1, C3, 0, 0, 0, 1.0f, 0);

    // 3. VWpT[b] = Wp^T @ V^T : [C1, T] bf16 (writes over dead xb region)
    gemm_bt<true><<<dim3(16, 8, 8), 256, 0, stream>>>(
        WprojT, qkvb + 2 * C1, VWpT, C1, C1, C3, T,
        0, (long long)T * C3, (long long)C1 * T, 1.0f, 0);

    // 4. attention, zc batches at a time
    for (int i = 0; i < Bb; i += zc) {
        const u16* qb   = qkvb + (long long)i * T * C3;
        const u16* kb   = qb + C1;
        const u16* vwpb = VWpT + (long long)i * C1 * T;
        float* ob = out + (long long)i * T * C1;

        // S = (q @ k^T) * C^-0.5, fp32 packed-triangular (136 blocks/batch);
        // zc=8: batch<->XCD remap inside the kernel (see gemm_bt header)
        gemm_bt<false><<<dim3(136, 1, zc), 256, 0, stream>>>(
            qb, kb, Sbuf, C1, C3, C3, 0,
            (long long)T * C3, (long long)T * C3, SPACK_ELEMS,
            0.03125f, 1);

        // A = causal softmax(S), bf16 in place within packed rows;
        // zc=8: batch<->XCD remap (reads S from the XCD that wrote it)
        softmax_causal_packed<<<dim3(T / 4, zc), 256, 0, stream>>>(
            Sbuf, SPACK_ELEMS);

        // out = A @ (V@Wp): A bf16 from packed S, B^T = VWpT [C,T], K kcap'd;
        // zc=8: batch<->XCD remap, round-5 form (bx fast / by slow = panel
        // adjacency; CU-targeted permutations measured neutral-to-negative)
        gemm_bt<false><<<dim3(8, 16, zc), 256, 0, stream>>>(
            (const u16*)Sbuf, vwpb, ob, T, 0, T, C1,
            2LL * SPACK_ELEMS, (long long)C1 * T, (long long)T * C1,
            1.0f, 2);
    }

    (void)in_sizes; (void)n_in; (void)out_size;
}

// Round 9
// 366.391 us; speedup vs baseline: 1.0547x; 1.0547x over previous
//
#include <hip/hip_runtime.h>

typedef unsigned short u16;
typedef __attribute__((ext_vector_type(8))) short bf16x8;   // 8 bf16 in 4 VGPRs
typedef __attribute__((ext_vector_type(4))) float f32x4;

__device__ __forceinline__ u16 f2bf(float f) {
    unsigned u = __float_as_uint(f);
    u += 0x7fffu + ((u >> 16) & 1u);   // round-to-nearest-even
    return (u16)(u >> 16);
}

__device__ __forceinline__ void g2l16(const void* g, void* l) {
    __builtin_amdgcn_global_load_lds((const __attribute__((address_space(1))) void*)g,
                                     (__attribute__((address_space(3))) void*)l, 16, 0, 0);
}

// Packed-triangular score layout (per batch, fp32 units):
//   block-row by (rows by*128..by*128+127) has row length L=(by+1)*128 and
//   base P(by) = 16384 * by*(by+1)/2.  Total = 16384*136 = 2,228,224 fp32
//   (8.9 MB/batch vs 16.8 dense) -> zc=8 fits in 204 MB of workspace.
#define SPACK_ELEMS 2228224LL

// ---------------------------------------------------------------------------
// GEMM: C[M,N] = alpha * A[M,K] @ B^T  where B is stored [N,K] row-major.
// bf16 in, fp32 accum. 128x128 tile, BK=64, 4 waves x (4x4 of 16x16x32 MFMA).
// 4 blocks/CU (32 KiB LDS) — inter-block overlap covers barrier drains
// (m114 mechanism); measured 46% MfmaUtil / ~1000 TF on the qkv shape.
// DO NOT: (a) 256^2 8-phase port (round 2: 34% MfmaUtil; needs full
// derived-waits schedule); (b) merge independent GEMMs into one launch
// (round 3: FETCH 144->509 MB); (c) split qkv M into two launches (round 5);
// (d) AV CU-targeted by-permutations (rounds 6-7: neutral-to-negative vs
// plain h>>3 — panel adjacency dominates).
//
// XCD PANEL PINNING (rounds 5+9; xcd = linear_id % 8 dispatch model VALIDATED
// by round 5's S-GEMM FETCH 215 -> 73 MB, 82 -> 57 us):
//  - modes 1/2, gridDim.z==8: batch = g&7 -> each XCD owns one batch
//    (working set 8-8.5 MB vs 4 MiB L2, panel clustering).
//  - mode 0, gridDim.z==8 (VWpT): batch = g&7; within XCD bx-fast so the
//    Wp row-panel (256 KB) is reused 16x; per-XCD set = Wp 2 MB + V 4 MB.
//  - mode 0, gridDim.z==1 (qkv, grid 24x128): XCD g&7 owns by-slab
//    [16*(g&7), +16), bx-major within slab -> x-slab 4 MB L2-resident,
//    W 6 MB streamed once per XCD. Mechanism: the m97-structure stall is
//    the vmcnt(0) drain = latency of the last staging load; L2 hits
//    (~200cy) instead of HBM misses (~900cy) shorten it.
//
// mode 0: plain grid (+ remaps above).
// mode 1: packed lower-triangle grid; C written into packed-triangular S.
// mode 2: K capped at (by+1)*128; A read from packed-tri S (bf16).
// ---------------------------------------------------------------------------
#define BM 128
#define BN 128
#define BK 64

template <bool OUT_BF16>
__global__ __launch_bounds__(256, 4) void gemm_bt(
    const u16* __restrict__ A, const u16* __restrict__ B, void* __restrict__ Cout,
    int K, int lda, int ldb, int ldc,
    long long sA, long long sB, long long sC,
    float alpha, int mode)
{
    int bx, by;
    int bz = blockIdx.z;
    if (mode == 1) {                       // packed triangle: l -> (bx<=by, by)
        int l;
        if (gridDim.z == 8) {              // batch<->XCD remap (see header)
            int g = (int)blockIdx.x + (int)gridDim.x * (int)blockIdx.z;
            bz = g & 7; l = g >> 3;        // l in [0, gridDim.x)
        } else {
            l = blockIdx.x;
        }
        by = (int)((sqrtf(8.f * (float)l + 1.f) - 1.f) * 0.5f);
        while ((by + 1) * (by + 2) / 2 <= l) ++by;
        while (by * (by + 1) / 2 > l) --by;
        bx = l - by * (by + 1) / 2;
    } else if (mode == 2) {                // causal K cap
        if (gridDim.z == 8) {              // batch<->XCD remap (round-5 form:
            int g = (int)blockIdx.x        //  bx fast, by slow -> same-by
                  + (int)gridDim.x * ((int)blockIdx.y   // blocks adjacent =
                  + (int)gridDim.y * (int)blockIdx.z);  // S-panel locality)
            bz = g & 7;
            int h = g >> 3;                // [0, 128)
            bx = h & 7;
            by = h >> 3;
        } else {                           // fallback: per-z row rotation
            bx = blockIdx.x;
            int byrev = ((int)blockIdx.y + 4 * ((int)blockIdx.z >> 1)) & 15;
            by = (int)gridDim.y - 1 - byrev;
        }
    } else {                               // mode 0
        if (gridDim.z == 8) {              // VWpT: batch<->XCD, bx-fast
            int g = (int)blockIdx.x
                  + (int)gridDim.x * ((int)blockIdx.y
                  + (int)gridDim.y * (int)blockIdx.z);
            bz = g & 7;
            int h = g >> 3;                // [0, gx*gy)
            bx = h & ((int)gridDim.x - 1); // gridDim.x == 16 (power of 2)
            by = h / (int)gridDim.x;
        } else if (gridDim.z == 1 && gridDim.y == 128 && gridDim.x == 24) {
            // qkv: XCD by-slab pinning, bx-major within slab
            int g = (int)blockIdx.x + 24 * (int)blockIdx.y;
            int s = g >> 3;                // [0, 384)
            by = (g & 7) * 16 + (s & 15);
            bx = s >> 4;                   // [0, 24)
        } else {
            bx = blockIdx.x; by = blockIdx.y;
        }
    }
    int Keff = K;
    if (mode == 2) { int cap = (by + 1) * BM; if (cap < Keff) Keff = cap; }

    __shared__ alignas(16) u16 As[BM * BK];
    __shared__ alignas(16) u16 Bs[BN * BK];

    const int tid  = threadIdx.x;
    const int wave = tid >> 6, lane = tid & 63;
    const int wm = wave >> 1, wn = wave & 1;
    const int q = lane >> 4, r = lane & 15;

    const long long Pby = 16384LL * (by * (by + 1) / 2);   // packed-tri base

    const u16* Ab;
    int lda_e = lda;
    if (mode == 2) {                       // A rows live in packed S (bf16 view)
        lda_e = 2 * (by + 1) * BM;         // u16 stride = fp32 row size
        Ab = A + sA * bz + 2 * Pby;
    } else {
        Ab = A + sA * bz + (size_t)(by * BM) * lda_e;
    }
    const u16* Bb = B + sB * bz + (size_t)(bx * BN) * ldb;

    // kt-invariant staging pointers (advance by BK elements per tile)
    const u16* ap[4]; const u16* bp[4]; int sb[4];
#pragma unroll
    for (int j = 0; j < 4; ++j) {
        int s   = (wave * 4 + j) * 64 + lane;
        int row = s >> 3;
        int cc  = (s & 7) ^ (row & 7);     // slot s holds global chunk cc of row
        ap[j] = Ab + (size_t)row * lda_e + cc * 8;
        bp[j] = Bb + (size_t)row * ldb + cc * 8;
        sb[j] = (wave * 4 + j) * 64;
    }

    f32x4 acc[4][4] = {};

    const int kiters = Keff / BK;
    for (int kt = 0; kt < kiters; ++kt) {
#pragma unroll
        for (int j = 0; j < 4; ++j) { g2l16(ap[j], As + (size_t)sb[j] * 8); ap[j] += BK; }
#pragma unroll
        for (int j = 0; j < 4; ++j) { g2l16(bp[j], Bs + (size_t)sb[j] * 8); bp[j] += BK; }
        __syncthreads();
#pragma unroll
        for (int ks = 0; ks < 2; ++ks) {   // two 32-wide k-steps per tile
            bf16x8 af[4], bfv[4];
#pragma unroll
            for (int i = 0; i < 4; ++i) {
                int mr = wm * 64 + i * 16 + r;
                int cc = (ks * 4 + q) ^ (mr & 7);
                af[i] = *(const bf16x8*)(As + mr * BK + cc * 8);
            }
#pragma unroll
            for (int i = 0; i < 4; ++i) {
                int nr = wn * 64 + i * 16 + r;
                int cc = (ks * 4 + q) ^ (nr & 7);
                bfv[i] = *(const bf16x8*)(Bs + nr * BK + cc * 8);
            }
#pragma unroll
            for (int i = 0; i < 4; ++i)
#pragma unroll
                for (int jn = 0; jn < 4; ++jn)
                    acc[i][jn] = __builtin_amdgcn_mfma_f32_16x16x32_bf16(
                        af[i], bfv[jn], acc[i][jn], 0, 0, 0);
        }
        __syncthreads();
    }

    // epilogue: C/D layout col=lane&15, row=(lane>>4)*4+reg
    if (mode == 1) {                       // packed-triangular fp32 write
        float* Cp = (float*)Cout + sC * bz + Pby;
        const int ldrow = (by + 1) * BM;
#pragma unroll
        for (int i = 0; i < 4; ++i) {
            int lr = wm * 64 + i * 16 + q * 4;            // local row in block-row
#pragma unroll
            for (int jn = 0; jn < 4; ++jn) {
                int col = bx * BN + wn * 64 + jn * 16 + r; // col < ldrow (bx<=by)
#pragma unroll
                for (int rr = 0; rr < 4; ++rr)
                    Cp[(size_t)(lr + rr) * ldrow + col] = acc[i][jn][rr] * alpha;
            }
        }
    } else if constexpr (OUT_BF16) {
        u16* Cp = (u16*)Cout + sC * bz;
#pragma unroll
        for (int i = 0; i < 4; ++i) {
            int rowb = by * BM + wm * 64 + i * 16 + q * 4;
#pragma unroll
            for (int jn = 0; jn < 4; ++jn) {
                int col = bx * BN + wn * 64 + jn * 16 + r;
#pragma unroll
                for (int rr = 0; rr < 4; ++rr)
                    Cp[(size_t)(rowb + rr) * ldc + col] = f2bf(acc[i][jn][rr] * alpha);
            }
        }
    } else {
        float* Cp = (float*)Cout + sC * bz;
#pragma unroll
        for (int i = 0; i < 4; ++i) {
            int rowb = by * BM + wm * 64 + i * 16 + q * 4;
#pragma unroll
            for (int jn = 0; jn < 4; ++jn) {
                int col = bx * BN + wn * 64 + jn * 16 + r;
#pragma unroll
                for (int rr = 0; rr < 4; ++rr)
                    Cp[(size_t)(rowb + rr) * ldc + col] = acc[i][jn][rr] * alpha;
            }
        }
    }
}

// ---------------------------------------------------------------------------
// Merged preprocessing (one launch instead of three): x cast + both weight
// transposes. Independent streaming jobs, whole-block divergence only,
// disjoint inputs/outputs -> no L2 coupling (unlike the round-3 GEMM merge).
// ---------------------------------------------------------------------------
__global__ __launch_bounds__(256) void pre_cast_all(
    const float* __restrict__ x,     u16* __restrict__ xb,
    const float* __restrict__ Wqkv,  u16* __restrict__ WqkvT,
    const float* __restrict__ Wproj, u16* __restrict__ WprojT)
{
    __shared__ u16 tile[32][33];
    const int b = blockIdx.x;
    if (b < 16384) {
        int i = b * 256 + threadIdx.x;
        float4 f = ((const float4*)x)[i];
        ushort4 o;
        o.x = f2bf(f.x); o.y = f2bf(f.y); o.z = f2bf(f.z); o.w = f2bf(f.w);
        ((ushort4*)xb)[i] = o;
        return;
    }
    const float* in; u16* out; int R, Cc, c0, r0;
    if (b < 16384 + 3072) {
        int l = b - 16384;                 // original grid (96, 32), x fast
        in = Wqkv; out = WqkvT; R = 1024; Cc = 3072;
        c0 = (l % 96) * 32; r0 = (l / 96) * 32;
    } else {
        int l = b - 16384 - 3072;          // original grid (32, 32), x fast
        in = Wproj; out = WprojT; R = 1024; Cc = 1024;
        c0 = (l % 32) * 32; r0 = (l / 32) * 32;
    }
    const int tx = threadIdx.x & 31, ty = threadIdx.x >> 5;   // 32 x 8
#pragma unroll
    for (int k = 0; k < 4; ++k)
        tile[ty + k * 8][tx] = f2bf(in[(size_t)(r0 + ty + k * 8) * Cc + c0 + tx]);
    __syncthreads();
#pragma unroll
    for (int k = 0; k < 4; ++k)
        out[(size_t)(c0 + ty + k * 8) * R + r0 + tx] = tile[tx][ty + k * 8];
}

// In-place causal softmax on the PACKED-triangular S, one WAVE per row.
// Row t (block-row by=t>>7) has length L=(by+1)*128 fp32 at
// S + z*sS + P(by) + (t&127)*L. Reads fp32 scores [0,t], writes bf16
// probabilities over the same bytes, zero-filling [t+1, L).
// gridDim.y == 8: batch<->XCD remap so batch b's rows run on the XCD whose
// L2 holds b's S (written there by the S-GEMM) and feeds the AV GEMM.
__global__ __launch_bounds__(256) void softmax_causal_packed(
    float* __restrict__ S, long long sS)
{
    const int wave = threadIdx.x >> 6, lane = threadIdx.x & 63;
    int zb, xb;
    if (gridDim.y == 8) {
        int g = (int)blockIdx.x + (int)gridDim.x * (int)blockIdx.y;
        zb = g & 7; xb = g >> 3;           // [0, gridDim.x)
    } else {
        zb = blockIdx.y; xb = blockIdx.x;
    }
    const int t = xb * 4 + wave;
    const int by = t >> 7, lr = t & 127;
    const int L = (by + 1) << 7;
    float* row = S + (long long)zb * sS
               + 16384LL * (by * (by + 1) / 2) + (size_t)lr * L;
    const int n = t + 1;
    const int nit = (L + 255) >> 8;        // chunks of 64 lanes x 4 floats, <=8

    float v[32];
    float m = -1e30f;
    for (int it = 0; it < nit; ++it) {
        int c = it * 64 + lane;
        int e = c * 4;
        float4 f = make_float4(-1e30f, -1e30f, -1e30f, -1e30f);
        if (e < n) f = ((const float4*)row)[c];
        v[it * 4 + 0] = (e + 0 < n) ? f.x : -1e30f;
        v[it * 4 + 1] = (e + 1 < n) ? f.y : -1e30f;
        v[it * 4 + 2] = (e + 2 < n) ? f.z : -1e30f;
        v[it * 4 + 3] = (e + 3 < n) ? f.w : -1e30f;
        m = fmaxf(m, fmaxf(fmaxf(v[it * 4 + 0], v[it * 4 + 1]),
                           fmaxf(v[it * 4 + 2], v[it * 4 + 3])));
    }
    for (int off = 32; off > 0; off >>= 1) m = fmaxf(m, __shfl_xor(m, off));

    float s = 0.f;
    for (int it = 0; it < nit; ++it) {
#pragma unroll
        for (int j = 0; j < 4; ++j) {
            v[it * 4 + j] = __expf(v[it * 4 + j] - m);
            s += v[it * 4 + j];
        }
    }
    for (int off = 32; off > 0; off >>= 1) s += __shfl_xor(s, off);
    float inv = 1.f / s;

    u16* orow = (u16*)row;
    for (int it = 0; it < nit; ++it) {
        int c = it * 64 + lane;
        if (c * 4 < L) {
            ushort4 o;
            o.x = f2bf(v[it * 4 + 0] * inv);
            o.y = f2bf(v[it * 4 + 1] * inv);
            o.z = f2bf(v[it * 4 + 2] * inv);
            o.w = f2bf(v[it * 4 + 3] * inv);
            ((ushort4*)orow)[c] = o;
        }
    }
}

extern "C" void kernel_launch(void* const* d_in, const int* in_sizes, int n_in,
                              void* d_out, int out_size, void* d_ws, size_t ws_size,
                              hipStream_t stream)
{
    const float* x     = (const float*)d_in[0];
    const float* Wqkv  = (const float*)d_in[1];
    const float* Wproj = (const float*)d_in[2];
    float* out = (float*)d_out;

    const int Bb = 8, T = 2048, C1 = 1024, C3 = 3072;

    // Reassociation: out = (A@V)@Wp = A@(V@Wp); VWpT[b] = Wp^T@V^T computed
    // right after qkv, replacing the vT transpose AND the final proj GEMM.
    // VWpT overlays xb (dead after qkv); S is packed-triangular (8.9 MB/batch)
    // so the zc=8 high-water mark is 204 MB.
    char* ws = (char*)d_ws;
    u16*  xb     = (u16*)(ws);                       //  32 MB  x bf16 (dead post-qkv)
    u16*  VWpT   = (u16*)(ws);                       //  32 MB  overlay [B][C, T]
    u16*  WqkvT  = (u16*)(ws +  33554432ULL);        //   6 MB  [3C, C]
    u16*  WprojT = (u16*)(ws +  39845888ULL);        //   2 MB  [C, C]
    u16*  qkvb   = (u16*)(ws +  41943040ULL);        //  96 MB  [B*T, 3C]
    float* Sbuf  = (float*)(ws + 142606336ULL);      //  zc * 8.9 MB packed scores

    // largest batch-chunk whose packed score buffer fits the workspace
    const unsigned long long sbytes = SPACK_ELEMS * 4ULL;   // 8,912,896 B/batch
    int zc = 1;
    if      (ws_size >= 142606336ULL + 8ULL * sbytes) zc = 8;
    else if (ws_size >= 142606336ULL + 4ULL * sbytes) zc = 4;
    else if (ws_size >= 142606336ULL + 2ULL * sbytes) zc = 2;

    // 1. merged preprocessing: x cast + Wqkv transpose + Wproj transpose
    pre_cast_all<<<16384 + 3072 + 1024, 256, 0, stream>>>(
        x, xb, Wqkv, WqkvT, Wproj, WprojT);

    // 2. qkv = x @ Wqkv   [16384,1024]x[1024,3072] -> bf16 [16384,3072]
    //    3072 blocks = 12/CU = 3 residency rounds; XCD by-slab pinning
    //    inside the kernel (x-slab L2-resident, shortens the vmcnt drain)
    gemm_bt<true><<<dim3(24, 128, 1), 256, 0, stream>>>(
        xb, WqkvT, qkvb, C1, C1, C1, C3, 0, 0, 0, 1.0f, 0);

    // 3. VWpT[b] = Wp^T @ V^T : [C1, T] bf16 (writes over dead xb region);
    //    batch<->XCD remap inside the kernel (Wp 2MB + V 4MB per XCD)
    gemm_bt<true><<<dim3(16, 8, 8), 256, 0, stream>>>(
        WprojT, qkvb + 2 * C1, VWpT, C1, C1, C3, T,
        0, (long long)T * C3, (long long)C1 * T, 1.0f, 0);

    // 4. attention, zc batches at a time
    for (int i = 0; i < Bb; i += zc) {
        const u16* qb   = qkvb + (long long)i * T * C3;
        const u16* kb   = qb + C1;
        const u16* vwpb = VWpT + (long long)i * C1 * T;
        float* ob = out + (long long)i * T * C1;

        // S = (q @ k^T) * C^-0.5, fp32 packed-triangular (136 blocks/batch);
        // zc=8: batch<->XCD remap inside the kernel (see gemm_bt header)
        gemm_bt<false><<<dim3(136, 1, zc), 256, 0, stream>>>(
            qb, kb, Sbuf, C1, C3, C3, 0,
            (long long)T * C3, (long long)T * C3, SPACK_ELEMS,
            0.03125f, 1);

        // A = causal softmax(S), bf16 in place within packed rows;
        // zc=8: batch<->XCD remap (reads S from the XCD that wrote it)
        softmax_causal_packed<<<dim3(T / 4, zc), 256, 0, stream>>>(
            Sbuf, SPACK_ELEMS);

        // out = A @ (V@Wp): A bf16 from packed S, B^T = VWpT [C,T], K kcap'd;
        // zc=8: batch<->XCD remap, round-5 form (bx fast / by slow = panel
        // adjacency; CU-targeted permutations measured neutral-to-negative)
        gemm_bt<false><<<dim3(8, 16, zc), 256, 0, stream>>>(
            (const u16*)Sbuf, vwpb, ob, T, 0, T, C1,
            2LL * SPACK_ELEMS, (long long)C1 * T, (long long)T * C1,
            1.0f, 2);
    }

    (void)in_sizes; (void)n_in; (void)out_size;
}